// Round 11
// baseline (312.464 us; speedup 1.0000x reference)
//
#include <hip/hip_runtime.h>
#include <hip/hip_bf16.h>
#include <stdint.h>

#define BQ   8
#define SEQ  2048
#define EMB  512
#define KVB  64     // keys per tile
#define HALF 1024   // keys per split-KV block
#define QTILE 128

typedef __attribute__((ext_vector_type(8)))  short short8;
typedef __attribute__((ext_vector_type(4)))  float floatx4;
typedef __attribute__((ext_vector_type(16))) float floatx16;
typedef __attribute__((ext_vector_type(4)))  unsigned short ushort4_t;
typedef __hip_bfloat16 bf16;

__device__ __forceinline__ unsigned short f2bf(float f) {
    union { bf16 h; unsigned short u; } c;
    c.h = __float2bfloat16(f);
    return c.u;
}
__device__ __forceinline__ float bf2f(unsigned short u) {
    union { unsigned int i; float f; } c;
    c.i = ((unsigned int)u) << 16;
    return c.f;
}

// ---------------- prep: cvt X, cvt W (scaled), mask->bias -----------------
__global__ __launch_bounds__(256) void prep(
    const float* __restrict__ feat,
    const float* __restrict__ Wq, const float* __restrict__ Wk,
    const float* __restrict__ Wv, const void* __restrict__ mraw,
    bf16* __restrict__ Xb, bf16* __restrict__ Wqb, bf16* __restrict__ Wkb,
    bf16* __restrict__ Wvb, float* __restrict__ bias, float qscale)
{
    __shared__ int bad;
    const int bx = blockIdx.x;
    const int tid = threadIdx.x;
    if (bx < 8192) {                        // X
        long i = (long)bx * 256 + tid;
        floatx4 v = ((const floatx4*)feat)[i];
        ushort4_t o;
        o.x = f2bf(v.x); o.y = f2bf(v.y); o.z = f2bf(v.z); o.w = f2bf(v.w);
        ((ushort4_t*)Xb)[i] = o;
    } else if (bx < 8960) {                 // W: 3 x 256 blocks
        int w = (bx - 8192) >> 8;
        int blk = (bx - 8192) & 255;
        const float* in = (w == 0) ? Wq : (w == 1) ? Wk : Wv;
        bf16* out = (w == 0) ? Wqb : (w == 1) ? Wkb : Wvb;
        float scale = (w == 0) ? qscale : 1.0f;
        long i = (long)blk * 256 + tid;
        floatx4 v = ((const floatx4*)in)[i];
        ushort4_t o;
        o.x = f2bf(v.x * scale); o.y = f2bf(v.y * scale);
        o.z = f2bf(v.z * scale); o.w = f2bf(v.w * scale);
        ((ushort4_t*)out)[i] = o;
    } else {                                // mask: 16 blocks
        if (tid == 0) bad = 0;
        __syncthreads();
        const int* mi = (const int*)mraw;
        int local = 0;
        for (int i = tid; i < 4096; i += 256) {
            unsigned v = (unsigned)mi[i];
            if (v > 1u) local = 1;
        }
        if (local) atomicOr(&bad, 1);
        __syncthreads();
        bool as_int = (bad == 0);
        const unsigned char* mb = (const unsigned char*)mraw;
        const int start = (bx - 8960) * (BQ * SEQ / 16);
        for (int i = start + tid; i < start + BQ * SEQ / 16; i += 256) {
            int mv = as_int ? mi[i] : (int)mb[i];
            bias[i] = mv ? -1e9f : -12.0f;   // static softmax base
        }
    }
}

// ---------------- fused QKV projection, BK=64 -----------------------------
// V output transposed + key bit2<->bit3 swap per 32-block (pa/A-frag order).
__global__ __launch_bounds__(256) void gemm_qkv(
    const bf16* __restrict__ X,
    const bf16* __restrict__ Wqb, const bf16* __restrict__ Wkb,
    const bf16* __restrict__ Wvb,
    bf16* __restrict__ Qd, bf16* __restrict__ Kd, bf16* __restrict__ Vtp)
{
    __shared__ __attribute__((aligned(16))) bf16 lA[128 * 64];
    __shared__ __attribute__((aligned(16))) bf16 lB[128 * 64];

    const int which = blockIdx.x >> 2;
    const bf16* Bt = (which == 0) ? Wqb : (which == 1) ? Wkb : Wvb;

    const int tid  = threadIdx.x;
    const int lane = tid & 63;
    const int wv   = tid >> 6;
    const int wr   = wv >> 1, wc = wv & 1;
    const long brow = (long)blockIdx.y * 128;
    const long bcol = (long)(blockIdx.x & 3) * 128;

    floatx4 acc[4][4];
#pragma unroll
    for (int m = 0; m < 4; m++)
#pragma unroll
        for (int n = 0; n < 4; n++) acc[m][n] = (floatx4)0.0f;

    const int hi  = lane >> 4;
    const int r16 = lane & 15;

    for (int kt = 0; kt < EMB; kt += 64) {
#pragma unroll
        for (int i = 0; i < 4; ++i) {
            int c = i * 256 + tid;
            int row = c >> 3, cc = c & 7;
            const bf16* src = X + (brow + row) * (long)EMB + kt + ((cc ^ (row & 7)) << 3);
            __builtin_amdgcn_global_load_lds(
                (const __attribute__((address_space(1))) void*)src,
                (__attribute__((address_space(3))) void*)(&lA[c * 8]),
                16, 0, 0);
        }
#pragma unroll
        for (int i = 0; i < 4; ++i) {
            int c = i * 256 + tid;
            int row = c >> 3, cc = c & 7;
            const bf16* src = Bt + (bcol + row) * (long)EMB + kt + ((cc ^ (row & 7)) << 3);
            __builtin_amdgcn_global_load_lds(
                (const __attribute__((address_space(1))) void*)src,
                (__attribute__((address_space(3))) void*)(&lB[c * 8]),
                16, 0, 0);
        }
        __syncthreads();

#pragma unroll
        for (int hh = 0; hh < 2; hh++) {
            short8 af[4], bfr[4];
#pragma unroll
            for (int m = 0; m < 4; m++) {
                int row = wr * 64 + m * 16 + r16;
                af[m] = *(const short8*)((const char*)lA + row * 128
                                         + (((hh * 4 + hi) ^ (row & 7)) << 4));
            }
#pragma unroll
            for (int n = 0; n < 4; n++) {
                int row = wc * 64 + n * 16 + r16;
                bfr[n] = *(const short8*)((const char*)lB + row * 128
                                          + (((hh * 4 + hi) ^ (row & 7)) << 4));
            }
#pragma unroll
            for (int m = 0; m < 4; m++)
#pragma unroll
                for (int n = 0; n < 4; n++)
                    acc[m][n] = __builtin_amdgcn_mfma_f32_16x16x32_bf16(
                        af[m], bfr[n], acc[m][n], 0, 0, 0);
        }
        __syncthreads();
    }

#pragma unroll
    for (int m = 0; m < 4; m++) {
#pragma unroll
        for (int n = 0; n < 4; n++) {
#pragma unroll
            for (int j = 0; j < 4; j++) {
                long row = brow + wr * 64 + m * 16 + hi * 4 + j;
                long col = bcol + wc * 64 + n * 16 + r16;
                float v = acc[m][n][j];
                if (which == 0) {
                    Qd[row * EMB + col] = __float2bfloat16(v);
                } else if (which == 1) {
                    Kd[row * EMB + col] = __float2bfloat16(v);
                } else {
                    // Vtp[b][e][key-pos]: pos = key with bits 2<->3 swapped
                    long bb = row >> 11;
                    int  t  = (int)(row & 2047);
                    int  t5 = t & 31;
                    int  tp = (t & ~31) | (t5 & 19)
                            | ((t5 & 4) << 1) | ((t5 & 8) >> 1);
                    Vtp[(bb * EMB + col) * SEQ + tp] = __float2bfloat16(v);
                }
            }
        }
    }
}

// ---------------- flash attention: 32x32 MFMA, static base ----------------
// grid 256: bid&7=batch, (bid>>3)&15=qtile(128), bid>>7=KV half. NT=16 x 64 keys.
// 8 waves: S-role (qg=wv&3, kh=wv>>2): S^T 32q x 32k via mfma_32x32x16(K,Q),
// lane(q=lane&31, h5=lane>>5) holds 16 P-values in A-frag order. Static-base
// exp, pa = C regs verbatim -> Plds (linear, conflict-free). PV-role
// (qg, eh=wv>>2): O 32q x 256e, A from Plds, B from transposed Vlds.
// K as [dchunk][key], V as [kslot][e] via reg-staging: all LDS reads linear.
__global__ __launch_bounds__(512, 2) void flash_attn(
    const bf16* __restrict__ Q, const bf16* __restrict__ K,
    const bf16* __restrict__ Vtp, const float* __restrict__ bias,
    bf16* __restrict__ part, float2* __restrict__ ml)
{
    __shared__ __attribute__((aligned(16))) char smem[65536 + 65536 + 16384 + 4096 + 1024];
    char*  smemK   = smem;                       // [64 dchunk][64 key] x16B
    char*  smemV   = smem + 65536;               // [8 kslot][512 e] x16B
    char*  smemP   = smem + 131072;              // [16 grp*s][64 lane] x16B
    float* biasLds = (float*)(smem + 147456);    // [1024]
    float* lLds    = (float*)(smem + 151552);    // [256]

    const int tid  = threadIdx.x;
    const int lane = tid & 63;
    const int wv   = tid >> 6;          // 0..7
    const int q31  = lane & 31, h5 = lane >> 5;
    const int qg   = wv & 3;            // q-group (both phases)
    const int kh   = wv >> 2;           // S: key-half; PV: e-half

    const int bid = blockIdx.x;
    const int b   = bid & 7;
    const int qt  = (bid >> 3) & 15;
    const int h   = bid >> 7;
    const long q0  = (long)qt * QTILE;
    const long kv0 = (long)h * HALF;
    const int NT   = HALF / KVB;        // 16

    const bf16* Qb = Q   + (long)b * SEQ * EMB;
    const bf16* Kb = K   + (long)b * SEQ * EMB + kv0 * EMB;
    const bf16* Vb = Vtp + (long)b * EMB * SEQ;
    const float* biasb = bias + (long)b * SEQ + kv0;

    if (tid < HALF / 4)
        ((floatx4*)biasLds)[tid] = ((const floatx4*)biasb)[tid];

    // per-lane Q row (B-operand): q = q0 + qg*32 + q31, elems k*16 + h5*8
    const bf16* qrow = Qb + (q0 + qg * 32 + q31) * EMB;

    floatx16 oacc[8];
#pragma unroll
    for (int et = 0; et < 8; et++) oacc[et] = (floatx16)0.f;
    float l_r = 0.f;

    // ---- reg-staging (T14: load early, ds_write after covering barrier) --
    short8 kreg[8], vreg[8];
    const int krow = tid >> 3, kseg = tid & 7;   // K: row 0..63, 128B seg

    auto loadK = [&](int t) {
        const bf16* src = Kb + ((long)t * KVB + krow) * EMB + kseg * 64;
#pragma unroll
        for (int i = 0; i < 8; i++) kreg[i] = *(const short8*)(src + i * 8);
    };
    auto writeK = [&]() {
#pragma unroll
        for (int i = 0; i < 8; i++)
            *(short8*)(smemK + (((kseg * 8 + i) * 64 + krow) << 4)) = kreg[i];
    };
    auto loadV = [&](int t) {
        const bf16* src = Vb + (long)tid * SEQ + kv0 + t * KVB;
#pragma unroll
        for (int i = 0; i < 8; i++) vreg[i] = *(const short8*)(src + i * 8);
    };
    auto writeV = [&]() {
#pragma unroll
        for (int i = 0; i < 8; i++)
            *(short8*)(smemV + (((i * 512 + tid)) << 4)) = vreg[i];
    };

    loadK(0); loadV(0);
    writeK();
    __syncthreads();                       // K(0) visible; V(0) in regs

    for (int t = 0; t < NT; t++) {
        writeV();                          // V(t) -> Vlds (drains by mid-bar)
        if (t + 1 < NT) loadK(t + 1);      // hides under S-phase

        // ---- S-phase: S^T = mfma32(K, Q), d-split chains ----
        floatx16 cA = (floatx16)0.f, cB = (floatx16)0.f;
        __builtin_amdgcn_s_setprio(1);
#pragma unroll
        for (int k = 0; k < 16; k++) {
            short8 kf = *(const short8*)(smemK + ((((k * 2 + h5) * 64) + kh * 32 + q31) << 4));
            short8 qf = *(const short8*)(qrow + k * 16 + h5 * 8);
            cA = __builtin_amdgcn_mfma_f32_32x32x16_bf16(kf, qf, cA, 0, 0, 0);
        }
#pragma unroll
        for (int k = 16; k < 32; k++) {
            short8 kf = *(const short8*)(smemK + ((((k * 2 + h5) * 64) + kh * 32 + q31) << 4));
            short8 qf = *(const short8*)(qrow + k * 16 + h5 * 8);
            cB = __builtin_amdgcn_mfma_f32_32x32x16_bf16(kf, qf, cB, 0, 0, 0);
        }
        __builtin_amdgcn_s_setprio(0);
        floatx16 c = cA + cB;

        // ---- static-base softmax: P = exp(s + bias), pa = C regs ----
        short8 pa0, pa1;
        float lp = 0.f;
#pragma unroll
        for (int r = 0; r < 16; r++) {
            int keyl = (r & 3) + 8 * (r >> 2) + 4 * h5;
            float p = __expf(c[r] + biasLds[t * KVB + kh * 32 + keyl]);
            lp += p;
            if (r < 8) pa0[r] = (short)f2bf(p);
            else       pa1[r - 8] = (short)f2bf(p);
        }
        l_r += lp;
        {
            int grp = qg * 2 + kh;
            *(short8*)(smemP + (((grp * 2 + 0) * 64 + lane) << 4)) = pa0;
            *(short8*)(smemP + (((grp * 2 + 1) * 64 + lane) << 4)) = pa1;
        }
        __syncthreads();                   // (b): P visible, V(t) landed, K reads done

        if (t + 1 < NT) { writeK(); loadV(t + 1); }  // K(t+1)->LDS; V(t+1)->regs

        // ---- PV-phase: O += P @ V over all 64 keys, wave's e-half ----
        __builtin_amdgcn_s_setprio(1);
#pragma unroll
        for (int st = 0; st < 4; st++) {
            int grp = qg * 2 + (st >> 1);
            short8 paf = *(const short8*)(smemP + (((grp * 2 + (st & 1)) * 64 + lane) << 4));
            int kslot = st * 2 + h5;
#pragma unroll
            for (int et = 0; et < 8; et++) {
                int e = kh * 256 + et * 32 + q31;
                short8 vf = *(const short8*)(smemV + ((kslot * 512 + e) << 4));
                oacc[et] = __builtin_amdgcn_mfma_f32_32x32x16_bf16(paf, vf, oacc[et], 0, 0, 0);
            }
        }
        __builtin_amdgcn_s_setprio(0);
        __syncthreads();                   // (d): V reads done, K(t+1) landed
    }

    // ---- epilogue: bf16 O partial + l per q-row ----
    bf16* pb = part + (long)bid * QTILE * EMB;
#pragma unroll
    for (int r = 0; r < 16; r++) {
        int qlocal = qg * 32 + (r & 3) + 8 * (r >> 2) + 4 * h5;
#pragma unroll
        for (int et = 0; et < 8; et++)
            pb[(long)qlocal * EMB + kh * 256 + et * 32 + q31] =
                __float2bfloat16(oacc[et][r]);
    }
    l_r += __shfl_xor(l_r, 32);
    if (h5 == 0) lLds[(qg * 2 + kh) * 32 + q31] = l_r;
    __syncthreads();
    if (wv < 4 && h5 == 0) {
        float lsum = lLds[(wv * 2 + 0) * 32 + q31] + lLds[(wv * 2 + 1) * 32 + q31];
        ml[(long)bid * QTILE + wv * 32 + q31] = make_float2(12.0f, lsum);
    }
}

// ---------------- combine the two KV halves (bf16 partials) ---------------
__global__ __launch_bounds__(128) void combine_halves(
    const bf16* __restrict__ part, const float2* __restrict__ ml,
    float* __restrict__ out)
{
    const int r  = blockIdx.x;
    const int b  = r >> 11;
    const int rb = r & 2047;
    const int qt = rb >> 7;
    const int rr = rb & 127;
    const int s0 = qt * 8 + b;
    const int s1 = s0 + 128;

    float2 ml0 = ml[(long)s0 * QTILE + rr];
    float2 ml1 = ml[(long)s1 * QTILE + rr];
    float M  = fmaxf(ml0.x, ml1.x);
    float w0 = __expf(ml0.x - M), w1 = __expf(ml1.x - M);
    float inv = 1.0f / (w0 * ml0.y + w1 * ml1.y);
    w0 *= inv; w1 *= inv;

    const ushort4_t* p0 = (const ushort4_t*)((const unsigned short*)part
                          + ((long)s0 * QTILE + rr) * EMB);
    const ushort4_t* p1 = (const ushort4_t*)((const unsigned short*)part
                          + ((long)s1 * QTILE + rr) * EMB);
    floatx4* po = (floatx4*)(out + (long)r * EMB);
    int c = threadIdx.x;
    ushort4_t a = p0[c], d = p1[c];
    floatx4 o;
    o.x = bf2f(a.x) * w0 + bf2f(d.x) * w1;
    o.y = bf2f(a.y) * w0 + bf2f(d.y) * w1;
    o.z = bf2f(a.z) * w0 + bf2f(d.z) * w1;
    o.w = bf2f(a.w) * w0 + bf2f(d.w) * w1;
    po[c] = o;
}

// --------------------------------------------------------------------------
extern "C" void kernel_launch(void* const* d_in, const int* in_sizes, int n_in,
                              void* d_out, int out_size, void* d_ws, size_t ws_size,
                              hipStream_t stream)
{
    const float* feat = (const float*)d_in[0];
    const void*  mask = d_in[1];
    const float* Wq   = (const float*)d_in[2];
    const float* Wk   = (const float*)d_in[3];
    const float* Wv   = (const float*)d_in[4];
    float* out = (float*)d_out;

    const long M  = (long)BQ * SEQ;
    const long NE = M * EMB;
    const long NW = (long)EMB * EMB;

    char* ws = (char*)d_ws;
    size_t off = 0;
    auto carve = [&](size_t bytes) -> void* {
        void* p = ws + off;
        off = (off + bytes + 4095) & ~(size_t)4095;
        return p;
    };
    bf16*   Xb   = (bf16*)carve(NE * 2);
    bf16*   Wqb  = (bf16*)carve(NW * 2);
    bf16*   Wkb  = (bf16*)carve(NW * 2);
    bf16*   Wvb  = (bf16*)carve(NW * 2);
    bf16*   Qb   = (bf16*)carve(NE * 2);
    bf16*   Kb   = (bf16*)carve(NE * 2);
    bf16*   Vtp  = (bf16*)carve(NE * 2);
    float*  bias = (float*)carve(M * 4);
    bf16*   part = (bf16*)carve((long)256 * QTILE * EMB * 2);   // 32MB
    float2* ml   = (float2*)carve((long)256 * QTILE * 8);
    (void)ws_size; (void)in_sizes; (void)n_in; (void)out_size;

    const float qscale = 0.04419417382415922f;  // 512^-0.5 folded into Wq

    prep<<<dim3(8976), dim3(256), 0, stream>>>(
        feat, Wq, Wk, Wv, mask, Xb, Wqb, Wkb, Wvb, bias, qscale);

    gemm_qkv<<<dim3(12, 128), dim3(256), 0, stream>>>(Xb, Wqb, Wkb, Wvb, Qb, Kb, Vtp);

    flash_attn<<<dim3(256), dim3(512), 0, stream>>>(Qb, Kb, Vtp, bias, part, ml);
    combine_halves<<<dim3(BQ * SEQ), dim3(128), 0, stream>>>(part, ml, out);
}

// Round 12
// 184.034 us; speedup vs baseline: 1.6979x; 1.6979x over previous
//
#include <hip/hip_runtime.h>
#include <hip/hip_bf16.h>
#include <stdint.h>

#define BQ   8
#define SEQ  2048
#define EMB  512
#define KVB  32
#define HALF 1024   // keys per split-KV block
#define QTILE 128

typedef __attribute__((ext_vector_type(8))) short short8;
typedef __attribute__((ext_vector_type(4))) float floatx4;
typedef __attribute__((ext_vector_type(4))) unsigned short ushort4_t;
typedef __hip_bfloat16 bf16;

__device__ __forceinline__ unsigned short f2bf(float f) {
    union { bf16 h; unsigned short u; } c;
    c.h = __float2bfloat16(f);
    return c.u;
}
__device__ __forceinline__ float bf2f(unsigned short u) {
    union { unsigned int i; float f; } c;
    c.i = ((unsigned int)u) << 16;
    return c.f;
}

// ---------------- prep: cvt X, cvt W (scaled), mask->bias -----------------
// grid.x = 8192 (X) + 768 (W) + 16 (mask) = 8976
__global__ __launch_bounds__(256) void prep(
    const float* __restrict__ feat,
    const float* __restrict__ Wq, const float* __restrict__ Wk,
    const float* __restrict__ Wv, const void* __restrict__ mraw,
    bf16* __restrict__ Xb, bf16* __restrict__ Wqb, bf16* __restrict__ Wkb,
    bf16* __restrict__ Wvb, float* __restrict__ bias, float qscale)
{
    __shared__ int bad;
    const int bx = blockIdx.x;
    const int tid = threadIdx.x;
    if (bx < 8192) {                        // X
        long i = (long)bx * 256 + tid;
        floatx4 v = ((const floatx4*)feat)[i];
        ushort4_t o;
        o.x = f2bf(v.x); o.y = f2bf(v.y); o.z = f2bf(v.z); o.w = f2bf(v.w);
        ((ushort4_t*)Xb)[i] = o;
    } else if (bx < 8960) {                 // W: 3 x 256 blocks
        int w = (bx - 8192) >> 8;
        int blk = (bx - 8192) & 255;
        const float* in = (w == 0) ? Wq : (w == 1) ? Wk : Wv;
        bf16* out = (w == 0) ? Wqb : (w == 1) ? Wkb : Wvb;
        float scale = (w == 0) ? qscale : 1.0f;
        long i = (long)blk * 256 + tid;
        floatx4 v = ((const floatx4*)in)[i];
        ushort4_t o;
        o.x = f2bf(v.x * scale); o.y = f2bf(v.y * scale);
        o.z = f2bf(v.z * scale); o.w = f2bf(v.w * scale);
        ((ushort4_t*)out)[i] = o;
    } else {                                // mask: 16 blocks
        if (tid == 0) bad = 0;
        __syncthreads();
        const int* mi = (const int*)mraw;
        int local = 0;
        for (int i = tid; i < 4096; i += 256) {
            unsigned v = (unsigned)mi[i];
            if (v > 1u) local = 1;
        }
        if (local) atomicOr(&bad, 1);
        __syncthreads();
        bool as_int = (bad == 0);
        const unsigned char* mb = (const unsigned char*)mraw;
        const int start = (bx - 8960) * (BQ * SEQ / 16);
        for (int i = start + tid; i < start + BQ * SEQ / 16; i += 256) {
            int mv = as_int ? mi[i] : (int)mb[i];
            bias[i] = mv ? -1e9f : -12.0f;   // static softmax base folded in
        }
    }
}

// ---------------- fused QKV projection, BK=64 (R9-verified) ---------------
__global__ __launch_bounds__(256) void gemm_qkv(
    const bf16* __restrict__ X,
    const bf16* __restrict__ Wqb, const bf16* __restrict__ Wkb,
    const bf16* __restrict__ Wvb,
    bf16* __restrict__ Qd, bf16* __restrict__ Kd, bf16* __restrict__ Vtp)
{
    __shared__ __attribute__((aligned(16))) bf16 lA[128 * 64];
    __shared__ __attribute__((aligned(16))) bf16 lB[128 * 64];

    const int which = blockIdx.x >> 2;
    const bf16* Bt = (which == 0) ? Wqb : (which == 1) ? Wkb : Wvb;

    const int tid  = threadIdx.x;
    const int lane = tid & 63;
    const int wv   = tid >> 6;
    const int wr   = wv >> 1, wc = wv & 1;
    const long brow = (long)blockIdx.y * 128;
    const long bcol = (long)(blockIdx.x & 3) * 128;

    floatx4 acc[4][4];
#pragma unroll
    for (int m = 0; m < 4; m++)
#pragma unroll
        for (int n = 0; n < 4; n++) acc[m][n] = (floatx4)0.0f;

    const int hi  = lane >> 4;
    const int r16 = lane & 15;

    for (int kt = 0; kt < EMB; kt += 64) {
#pragma unroll
        for (int i = 0; i < 4; ++i) {
            int c = i * 256 + tid;
            int row = c >> 3, cc = c & 7;
            const bf16* src = X + (brow + row) * (long)EMB + kt + ((cc ^ (row & 7)) << 3);
            __builtin_amdgcn_global_load_lds(
                (const __attribute__((address_space(1))) void*)src,
                (__attribute__((address_space(3))) void*)(&lA[c * 8]),
                16, 0, 0);
        }
#pragma unroll
        for (int i = 0; i < 4; ++i) {
            int c = i * 256 + tid;
            int row = c >> 3, cc = c & 7;
            const bf16* src = Bt + (bcol + row) * (long)EMB + kt + ((cc ^ (row & 7)) << 3);
            __builtin_amdgcn_global_load_lds(
                (const __attribute__((address_space(1))) void*)src,
                (__attribute__((address_space(3))) void*)(&lB[c * 8]),
                16, 0, 0);
        }
        __syncthreads();

#pragma unroll
        for (int hh = 0; hh < 2; hh++) {
            short8 af[4], bfr[4];
#pragma unroll
            for (int m = 0; m < 4; m++) {
                int row = wr * 64 + m * 16 + r16;
                af[m] = *(const short8*)((const char*)lA + row * 128
                                         + (((hh * 4 + hi) ^ (row & 7)) << 4));
            }
#pragma unroll
            for (int n = 0; n < 4; n++) {
                int row = wc * 64 + n * 16 + r16;
                bfr[n] = *(const short8*)((const char*)lB + row * 128
                                          + (((hh * 4 + hi) ^ (row & 7)) << 4));
            }
#pragma unroll
            for (int m = 0; m < 4; m++)
#pragma unroll
                for (int n = 0; n < 4; n++)
                    acc[m][n] = __builtin_amdgcn_mfma_f32_16x16x32_bf16(
                        af[m], bfr[n], acc[m][n], 0, 0, 0);
        }
        __syncthreads();
    }

#pragma unroll
    for (int m = 0; m < 4; m++) {
#pragma unroll
        for (int n = 0; n < 4; n++) {
#pragma unroll
            for (int j = 0; j < 4; j++) {
                long row = brow + wr * 64 + m * 16 + hi * 4 + j;
                long col = bcol + wc * 64 + n * 16 + r16;
                float v = acc[m][n][j];
                if (which == 0) {
                    Qd[row * EMB + col] = __float2bfloat16(v);
                } else if (which == 1) {
                    Kd[row * EMB + col] = __float2bfloat16(v);
                } else {
                    // Vtp[b][e][key], keys pi-permuted per 32-block:
                    // pos = ((k>>2)&3)*8 + ((k>>4)&1)*4 + (k&3)
                    long bb = row >> 11;
                    int  t  = (int)(row & 2047);
                    int  t5 = t & 31;
                    int  tp = (t & ~31) | (((t5 >> 2) & 3) << 3)
                            | (((t5 >> 4) & 1) << 2) | (t5 & 3);
                    Vtp[(bb * EMB + col) * SEQ + tp] = __float2bfloat16(v);
                }
            }
        }
    }
}

// ---------------- fused flash attention (R9 structure + static base) ------
// grid 256: bid&7=batch (XCD), (bid>>3)&15=qtile(128 rows), bid>>7=KV half.
// Wave w owns q-rows q0+w*16..+15 (all 512 e-cols). S^T = mfma(K,Q):
// lane(hi,r16) holds P[q=w*16+r16][keys {4hi+j, 16+4hi+j}]. Static base:
// P = exp(s + bias), bias pre-shifted by -12 -> no max tracking/rescale.
// PV: pa=[p0,p1] bf16; B-frag = ONE b128 from key-permuted Vlds.
// K,V double-buffered LDS; 1 barrier/tile. V rotation (col>>1)&3.
__global__ __launch_bounds__(512) void flash_attn(
    const bf16* __restrict__ Q, const bf16* __restrict__ K,
    const bf16* __restrict__ Vtp, const float* __restrict__ bias,
    bf16* __restrict__ part, float2* __restrict__ ml)
{
    __shared__ __attribute__((aligned(16))) char smem[2 * 32768 + 2 * 32768 + HALF * 4];
    bf16* Klds0 = (bf16*)smem;                         // [2][32*512]
    bf16* Vlds0 = (bf16*)(smem + 65536);               // [2][512*32] permuted keys
    float* biasLds = (float*)(smem + 131072);          // [1024]

    const int tid  = threadIdx.x;
    const int lane = tid & 63;
    const int wv   = tid >> 6;          // 0..7
    const int r16  = lane & 15, hi = lane >> 4;

    const int bid = blockIdx.x;
    const int b   = bid & 7;            // batch -> XCD
    const int qt  = (bid >> 3) & 15;    // 0..15
    const int h   = bid >> 7;           // KV half
    const long q0  = (long)qt * QTILE;
    const long kv0 = (long)h * HALF;
    const int NT   = HALF / KVB;        // 32

    const bf16* Qb = Q   + (long)b * SEQ * EMB;
    const bf16* Kb = K   + (long)b * SEQ * EMB + kv0 * EMB;
    const bf16* Vb = Vtp + (long)b * EMB * SEQ;
    const float* biasb = bias + (long)b * SEQ + kv0;

    if (tid < HALF / 4)
        *(floatx4*)&biasLds[tid * 4] = *(const floatx4*)&biasb[tid * 4];

    // ALL 16 Q fragments hoisted (static base freed the register headroom)
    const bf16* qrow = Qb + (q0 + wv * 16 + r16) * EMB;
    short8 qf[16];
#pragma unroll
    for (int ks = 0; ks < 16; ks++)
        qf[ks] = *(const short8*)(qrow + ks * 32 + hi * 8);

    floatx4 oacc[32];
#pragma unroll
    for (int nf = 0; nf < 32; nf++) oacc[nf] = (floatx4)0.f;

    float l_r = 0.f;

    // stage K tile (32x512, XOR-swz chunks) + V tile (512x32 permuted,
    // 16B-chunk rotation by (col>>1)&3). 8 x global_load_lds per thread.
    auto stage = [&](int buf, int t) {
        bf16* kd = Klds0 + buf * (KVB * EMB);
        bf16* vd = Vlds0 + buf * (EMB * KVB);
#pragma unroll
        for (int i = 0; i < 4; i++) {
            int c = i * 512 + tid;          // K chunk id
            int row = c >> 6, cc = c & 63;
            const bf16* src = Kb + ((long)t * KVB + row) * EMB + ((cc ^ (row & 7)) << 3);
            __builtin_amdgcn_global_load_lds(
                (const __attribute__((address_space(1))) void*)src,
                (__attribute__((address_space(3))) void*)(kd + c * 8),
                16, 0, 0);
        }
#pragma unroll
        for (int i = 0; i < 4; i++) {
            int c = i * 512 + tid;          // V chunk id
            int col = c >> 2, ch = c & 3;
            const bf16* src = Vb + (long)col * SEQ + kv0 + t * KVB
                            + ((ch ^ ((col >> 1) & 3)) << 3);
            __builtin_amdgcn_global_load_lds(
                (const __attribute__((address_space(1))) void*)src,
                (__attribute__((address_space(3))) void*)(vd + c * 8),
                16, 0, 0);
        }
    };

    stage(0, 0);
    __syncthreads();

    for (int t = 0; t < NT; t++) {
        const int cur = t & 1;
        if (t + 1 < NT) stage(cur ^ 1, t + 1);

        // ---- S^T = mfma(A=K, B=Q): c0 keys 0..15, c1 keys 16..31 ----
        floatx4 c0 = (floatx4)0.f, c1 = (floatx4)0.f;
        const char* kbase = (const char*)(Klds0 + cur * (KVB * EMB));
        const int rowb0 = r16 * 1024, rowb1 = rowb0 + 16 * 1024;
        const int sw = r16 & 7;
        __builtin_amdgcn_s_setprio(1);
#pragma unroll
        for (int ks = 0; ks < 16; ks++) {
            const int cc = ((ks * 4 + hi) ^ sw) << 4;
            short8 k0 = *(const short8*)(kbase + rowb0 + cc);
            c0 = __builtin_amdgcn_mfma_f32_16x16x32_bf16(k0, qf[ks], c0, 0, 0, 0);
            short8 k1 = *(const short8*)(kbase + rowb1 + cc);
            c1 = __builtin_amdgcn_mfma_f32_16x16x32_bf16(k1, qf[ks], c1, 0, 0, 0);
        }
        __builtin_amdgcn_s_setprio(0);

        // ---- static-base softmax: P = exp(s + bias), no max tracking ----
        float p0[4], p1[4], rsum = 0.f;
#pragma unroll
        for (int j = 0; j < 4; j++) {
            p0[j] = __expf(c0[j] + biasLds[t * KVB + hi * 4 + j]);
            p1[j] = __expf(c1[j] + biasLds[t * KVB + 16 + hi * 4 + j]);
            rsum += p0[j] + p1[j];
        }
        rsum += __shfl_xor(rsum, 16);
        rsum += __shfl_xor(rsum, 32);
        l_r += rsum;

        short8 pa;                                 // slots [p0, p1] match Vtp perm
#pragma unroll
        for (int j = 0; j < 4; j++) {
            pa[j]     = (short)f2bf(p0[j]);
            pa[4 + j] = (short)f2bf(p1[j]);
        }

        // ---- O += P @ V: B-frag = one b128 from permuted Vlds ----
        const char* vbase = (const char*)(Vlds0 + cur * (EMB * KVB));
        __builtin_amdgcn_s_setprio(1);
#pragma unroll
        for (int cf = 0; cf < 32; cf++) {
            const int col = cf * 16 + r16;
            short8 vf = *(const short8*)(vbase + col * 64 + ((hi ^ ((col >> 1) & 3)) << 4));
            oacc[cf] = __builtin_amdgcn_mfma_f32_16x16x32_bf16(pa, vf, oacc[cf], 0, 0, 0);
        }
        __builtin_amdgcn_s_setprio(0);

        __syncthreads();   // staged t+1 drained; buffers swappable
    }

    // ---- epilogue: unnormalized bf16 O partial + (m=12, l) per q-row ----
    bf16* pb = part + (long)bid * QTILE * EMB;
#pragma unroll
    for (int j = 0; j < 4; j++) {
        long row = wv * 16 + hi * 4 + j;
#pragma unroll
        for (int cf = 0; cf < 32; cf++)
            pb[row * EMB + cf * 16 + r16] = __float2bfloat16(oacc[cf][j]);
    }
    if (hi == 0)
        ml[(long)bid * QTILE + wv * 16 + r16] = make_float2(12.0f, l_r);
}

// ---------------- combine the two KV halves (bf16 partials) ---------------
__global__ __launch_bounds__(128) void combine_halves(
    const bf16* __restrict__ part, const float2* __restrict__ ml,
    float* __restrict__ out)
{
    const int r  = blockIdx.x;              // 0..16383 global q-row
    const int b  = r >> 11;
    const int rb = r & 2047;
    const int qt = rb >> 7;
    const int rr = rb & 127;
    const int s0 = qt * 8 + b;              // slot of half 0
    const int s1 = s0 + 128;

    float2 ml0 = ml[(long)s0 * QTILE + rr];
    float2 ml1 = ml[(long)s1 * QTILE + rr];
    float M  = fmaxf(ml0.x, ml1.x);
    float w0 = __expf(ml0.x - M), w1 = __expf(ml1.x - M);
    float inv = 1.0f / (w0 * ml0.y + w1 * ml1.y);
    w0 *= inv; w1 *= inv;

    const ushort4_t* p0 = (const ushort4_t*)((const unsigned short*)part
                          + ((long)s0 * QTILE + rr) * EMB);
    const ushort4_t* p1 = (const ushort4_t*)((const unsigned short*)part
                          + ((long)s1 * QTILE + rr) * EMB);
    floatx4* po = (floatx4*)(out + (long)r * EMB);
    int c = threadIdx.x;                    // 128 threads x 4 = 512
    ushort4_t a = p0[c], d = p1[c];
    floatx4 o;
    o.x = bf2f(a.x) * w0 + bf2f(d.x) * w1;
    o.y = bf2f(a.y) * w0 + bf2f(d.y) * w1;
    o.z = bf2f(a.z) * w0 + bf2f(d.z) * w1;
    o.w = bf2f(a.w) * w0 + bf2f(d.w) * w1;
    po[c] = o;
}

// --------------------------------------------------------------------------
extern "C" void kernel_launch(void* const* d_in, const int* in_sizes, int n_in,
                              void* d_out, int out_size, void* d_ws, size_t ws_size,
                              hipStream_t stream)
{
    const float* feat = (const float*)d_in[0];
    const void*  mask = d_in[1];
    const float* Wq   = (const float*)d_in[2];
    const float* Wk   = (const float*)d_in[3];
    const float* Wv   = (const float*)d_in[4];
    float* out = (float*)d_out;

    const long M  = (long)BQ * SEQ;
    const long NE = M * EMB;
    const long NW = (long)EMB * EMB;

    char* ws = (char*)d_ws;
    size_t off = 0;
    auto carve = [&](size_t bytes) -> void* {
        void* p = ws + off;
        off = (off + bytes + 4095) & ~(size_t)4095;
        return p;
    };
    bf16*   Xb   = (bf16*)carve(NE * 2);
    bf16*   Wqb  = (bf16*)carve(NW * 2);
    bf16*   Wkb  = (bf16*)carve(NW * 2);
    bf16*   Wvb  = (bf16*)carve(NW * 2);
    bf16*   Qb   = (bf16*)carve(NE * 2);
    bf16*   Kb   = (bf16*)carve(NE * 2);
    bf16*   Vtp  = (bf16*)carve(NE * 2);
    float*  bias = (float*)carve(M * 4);
    bf16*   part = (bf16*)carve((long)256 * QTILE * EMB * 2);   // 32MB
    float2* ml   = (float2*)carve((long)256 * QTILE * 8);
    (void)ws_size; (void)in_sizes; (void)n_in; (void)out_size;

    const float qscale = 0.04419417382415922f;  // 512^-0.5 folded into Wq

    prep<<<dim3(8976), dim3(256), 0, stream>>>(
        feat, Wq, Wk, Wv, mask, Xb, Wqb, Wkb, Wvb, bias, qscale);

    gemm_qkv<<<dim3(12, 128), dim3(256), 0, stream>>>(Xb, Wqb, Wkb, Wvb, Qb, Kb, Vtp);

    flash_attn<<<dim3(256), dim3(512), 0, stream>>>(Qb, Kb, Vtp, bias, part, ml);
    combine_halves<<<dim3(BQ * SEQ), dim3(128), 0, stream>>>(part, ml, out);
}

// Round 13
// 182.784 us; speedup vs baseline: 1.7095x; 1.0068x over previous
//
#include <hip/hip_runtime.h>
#include <hip/hip_bf16.h>
#include <stdint.h>

#define BQ   8
#define SEQ  2048
#define EMB  512
#define KVB  32
#define HALF 1024   // keys per split-KV block
#define QTILE 128

typedef __attribute__((ext_vector_type(8))) short short8;
typedef __attribute__((ext_vector_type(4))) float floatx4;
typedef __attribute__((ext_vector_type(4))) unsigned short ushort4_t;
typedef __hip_bfloat16 bf16;

__device__ __forceinline__ unsigned short f2bf(float f) {
    union { bf16 h; unsigned short u; } c;
    c.h = __float2bfloat16(f);
    return c.u;
}
__device__ __forceinline__ float bf2f(unsigned short u) {
    union { unsigned int i; float f; } c;
    c.i = ((unsigned int)u) << 16;
    return c.f;
}
__device__ __forceinline__ float exp2_fast(float x) {
    float r;
    asm("v_exp_f32 %0, %1" : "=v"(r) : "v"(x));
    return r;
}

// ---------------- prep: cvt X, cvt W (scaled), mask->bias -----------------
// grid.x = 8192 (X) + 768 (W) + 16 (mask) = 8976
// Base-2 softmax: log2e folded into qscale and bias constants.
__global__ __launch_bounds__(256) void prep(
    const float* __restrict__ feat,
    const float* __restrict__ Wq, const float* __restrict__ Wk,
    const float* __restrict__ Wv, const void* __restrict__ mraw,
    bf16* __restrict__ Xb, bf16* __restrict__ Wqb, bf16* __restrict__ Wkb,
    bf16* __restrict__ Wvb, float* __restrict__ bias, float qscale)
{
    __shared__ int bad;
    const int bx = blockIdx.x;
    const int tid = threadIdx.x;
    if (bx < 8192) {                        // X
        long i = (long)bx * 256 + tid;
        floatx4 v = ((const floatx4*)feat)[i];
        ushort4_t o;
        o.x = f2bf(v.x); o.y = f2bf(v.y); o.z = f2bf(v.z); o.w = f2bf(v.w);
        ((ushort4_t*)Xb)[i] = o;
    } else if (bx < 8960) {                 // W: 3 x 256 blocks
        int w = (bx - 8192) >> 8;
        int blk = (bx - 8192) & 255;
        const float* in = (w == 0) ? Wq : (w == 1) ? Wk : Wv;
        bf16* out = (w == 0) ? Wqb : (w == 1) ? Wkb : Wvb;
        float scale = (w == 0) ? qscale : 1.0f;
        long i = (long)blk * 256 + tid;
        floatx4 v = ((const floatx4*)in)[i];
        ushort4_t o;
        o.x = f2bf(v.x * scale); o.y = f2bf(v.y * scale);
        o.z = f2bf(v.z * scale); o.w = f2bf(v.w * scale);
        ((ushort4_t*)out)[i] = o;
    } else {                                // mask: 16 blocks
        if (tid == 0) bad = 0;
        __syncthreads();
        const int* mi = (const int*)mraw;
        int local = 0;
        for (int i = tid; i < 4096; i += 256) {
            unsigned v = (unsigned)mi[i];
            if (v > 1u) local = 1;
        }
        if (local) atomicOr(&bad, 1);
        __syncthreads();
        bool as_int = (bad == 0);
        const unsigned char* mb = (const unsigned char*)mraw;
        const int start = (bx - 8960) * (BQ * SEQ / 16);
        for (int i = start + tid; i < start + BQ * SEQ / 16; i += 256) {
            int mv = as_int ? mi[i] : (int)mb[i];
            // static base -12 in e-units -> -12*log2e in base-2 units
            bias[i] = mv ? -1e9f : -17.312340490667560f;
        }
    }
}

// ---------------- fused QKV projection, BK=64 (R9-verified) ---------------
__global__ __launch_bounds__(256) void gemm_qkv(
    const bf16* __restrict__ X,
    const bf16* __restrict__ Wqb, const bf16* __restrict__ Wkb,
    const bf16* __restrict__ Wvb,
    bf16* __restrict__ Qd, bf16* __restrict__ Kd, bf16* __restrict__ Vtp)
{
    __shared__ __attribute__((aligned(16))) bf16 lA[128 * 64];
    __shared__ __attribute__((aligned(16))) bf16 lB[128 * 64];

    const int which = blockIdx.x >> 2;
    const bf16* Bt = (which == 0) ? Wqb : (which == 1) ? Wkb : Wvb;

    const int tid  = threadIdx.x;
    const int lane = tid & 63;
    const int wv   = tid >> 6;
    const int wr   = wv >> 1, wc = wv & 1;
    const long brow = (long)blockIdx.y * 128;
    const long bcol = (long)(blockIdx.x & 3) * 128;

    floatx4 acc[4][4];
#pragma unroll
    for (int m = 0; m < 4; m++)
#pragma unroll
        for (int n = 0; n < 4; n++) acc[m][n] = (floatx4)0.0f;

    const int hi  = lane >> 4;
    const int r16 = lane & 15;

    for (int kt = 0; kt < EMB; kt += 64) {
#pragma unroll
        for (int i = 0; i < 4; ++i) {
            int c = i * 256 + tid;
            int row = c >> 3, cc = c & 7;
            const bf16* src = X + (brow + row) * (long)EMB + kt + ((cc ^ (row & 7)) << 3);
            __builtin_amdgcn_global_load_lds(
                (const __attribute__((address_space(1))) void*)src,
                (__attribute__((address_space(3))) void*)(&lA[c * 8]),
                16, 0, 0);
        }
#pragma unroll
        for (int i = 0; i < 4; ++i) {
            int c = i * 256 + tid;
            int row = c >> 3, cc = c & 7;
            const bf16* src = Bt + (bcol + row) * (long)EMB + kt + ((cc ^ (row & 7)) << 3);
            __builtin_amdgcn_global_load_lds(
                (const __attribute__((address_space(1))) void*)src,
                (__attribute__((address_space(3))) void*)(&lB[c * 8]),
                16, 0, 0);
        }
        __syncthreads();

#pragma unroll
        for (int hh = 0; hh < 2; hh++) {
            short8 af[4], bfr[4];
#pragma unroll
            for (int m = 0; m < 4; m++) {
                int row = wr * 64 + m * 16 + r16;
                af[m] = *(const short8*)((const char*)lA + row * 128
                                         + (((hh * 4 + hi) ^ (row & 7)) << 4));
            }
#pragma unroll
            for (int n = 0; n < 4; n++) {
                int row = wc * 64 + n * 16 + r16;
                bfr[n] = *(const short8*)((const char*)lB + row * 128
                                          + (((hh * 4 + hi) ^ (row & 7)) << 4));
            }
#pragma unroll
            for (int m = 0; m < 4; m++)
#pragma unroll
                for (int n = 0; n < 4; n++)
                    acc[m][n] = __builtin_amdgcn_mfma_f32_16x16x32_bf16(
                        af[m], bfr[n], acc[m][n], 0, 0, 0);
        }
        __syncthreads();
    }

#pragma unroll
    for (int m = 0; m < 4; m++) {
#pragma unroll
        for (int n = 0; n < 4; n++) {
#pragma unroll
            for (int j = 0; j < 4; j++) {
                long row = brow + wr * 64 + m * 16 + hi * 4 + j;
                long col = bcol + wc * 64 + n * 16 + r16;
                float v = acc[m][n][j];
                if (which == 0) {
                    Qd[row * EMB + col] = __float2bfloat16(v);
                } else if (which == 1) {
                    Kd[row * EMB + col] = __float2bfloat16(v);
                } else {
                    // Vtp[b][e][key], keys pi-permuted per 32-block:
                    // pos = ((k>>2)&3)*8 + ((k>>4)&1)*4 + (k&3)
                    long bb = row >> 11;
                    int  t  = (int)(row & 2047);
                    int  t5 = t & 31;
                    int  tp = (t & ~31) | (((t5 >> 2) & 3) << 3)
                            | (((t5 >> 4) & 1) << 2) | (t5 & 3);
                    Vtp[(bb * EMB + col) * SEQ + tp] = __float2bfloat16(v);
                }
            }
        }
    }
}

// ---------------- fused flash attention (R12 + base-2 micro-cuts) ---------
// grid 256: bid&7=batch (XCD), (bid>>3)&15=qtile(128 rows), bid>>7=KV half.
// Wave w owns q-rows q0+w*16..+15 (all 512 e-cols). S^T = mfma(K,Q), 4
// independent MFMA chains. Static base-2 softmax: P = 2^(s'+b'), no max
// tracking; per-lane l partials, single reduce at epilogue.
// PV: pa=[p0,p1] bf16; B-frag = ONE b128 from key-permuted Vlds.
// K,V double-buffered LDS; 1 barrier/tile. V rotation (col>>1)&3.
__global__ __launch_bounds__(512) void flash_attn(
    const bf16* __restrict__ Q, const bf16* __restrict__ K,
    const bf16* __restrict__ Vtp, const float* __restrict__ bias,
    bf16* __restrict__ part, float2* __restrict__ ml)
{
    __shared__ __attribute__((aligned(16))) char smem[2 * 32768 + 2 * 32768 + HALF * 4];
    bf16* Klds0 = (bf16*)smem;                         // [2][32*512]
    bf16* Vlds0 = (bf16*)(smem + 65536);               // [2][512*32] permuted keys
    float* biasLds = (float*)(smem + 131072);          // [1024]

    const int tid  = threadIdx.x;
    const int lane = tid & 63;
    const int wv   = tid >> 6;          // 0..7
    const int r16  = lane & 15, hi = lane >> 4;

    const int bid = blockIdx.x;
    const int b   = bid & 7;            // batch -> XCD
    const int qt  = (bid >> 3) & 15;    // 0..15
    const int h   = bid >> 7;           // KV half
    const long q0  = (long)qt * QTILE;
    const long kv0 = (long)h * HALF;
    const int NT   = HALF / KVB;        // 32

    const bf16* Qb = Q   + (long)b * SEQ * EMB;
    const bf16* Kb = K   + (long)b * SEQ * EMB + kv0 * EMB;
    const bf16* Vb = Vtp + (long)b * EMB * SEQ;
    const float* biasb = bias + (long)b * SEQ + kv0;

    if (tid < HALF / 4)
        *(floatx4*)&biasLds[tid * 4] = *(const floatx4*)&biasb[tid * 4];

    // ALL 16 Q fragments hoisted
    const bf16* qrow = Qb + (q0 + wv * 16 + r16) * EMB;
    short8 qf[16];
#pragma unroll
    for (int ks = 0; ks < 16; ks++)
        qf[ks] = *(const short8*)(qrow + ks * 32 + hi * 8);

    floatx4 oacc[32];
#pragma unroll
    for (int nf = 0; nf < 32; nf++) oacc[nf] = (floatx4)0.f;

    float l_r = 0.f;                    // per-lane partial; reduced at end

    // stage K tile (32x512, XOR-swz chunks) + V tile (512x32 permuted,
    // 16B-chunk rotation by (col>>1)&3). 8 x global_load_lds per thread.
    auto stage = [&](int buf, int t) {
        bf16* kd = Klds0 + buf * (KVB * EMB);
        bf16* vd = Vlds0 + buf * (EMB * KVB);
#pragma unroll
        for (int i = 0; i < 4; i++) {
            int c = i * 512 + tid;          // K chunk id
            int row = c >> 6, cc = c & 63;
            const bf16* src = Kb + ((long)t * KVB + row) * EMB + ((cc ^ (row & 7)) << 3);
            __builtin_amdgcn_global_load_lds(
                (const __attribute__((address_space(1))) void*)src,
                (__attribute__((address_space(3))) void*)(kd + c * 8),
                16, 0, 0);
        }
#pragma unroll
        for (int i = 0; i < 4; i++) {
            int c = i * 512 + tid;          // V chunk id
            int col = c >> 2, ch = c & 3;
            const bf16* src = Vb + (long)col * SEQ + kv0 + t * KVB
                            + ((ch ^ ((col >> 1) & 3)) << 3);
            __builtin_amdgcn_global_load_lds(
                (const __attribute__((address_space(1))) void*)src,
                (__attribute__((address_space(3))) void*)(vd + c * 8),
                16, 0, 0);
        }
    };

    stage(0, 0);
    __syncthreads();

    for (int t = 0; t < NT; t++) {
        const int cur = t & 1;
        if (t + 1 < NT) stage(cur ^ 1, t + 1);

        // ---- S^T = mfma(A=K, B=Q): 4 independent chains ----
        floatx4 c0a = (floatx4)0.f, c0b = (floatx4)0.f;
        floatx4 c1a = (floatx4)0.f, c1b = (floatx4)0.f;
        const char* kbase = (const char*)(Klds0 + cur * (KVB * EMB));
        const int rowb0 = r16 * 1024, rowb1 = rowb0 + 16 * 1024;
        const int sw = r16 & 7;
        __builtin_amdgcn_s_setprio(1);
#pragma unroll
        for (int ks = 0; ks < 16; ks += 2) {
            const int cc0 = ((ks * 4 + hi) ^ sw) << 4;
            short8 k00 = *(const short8*)(kbase + rowb0 + cc0);
            c0a = __builtin_amdgcn_mfma_f32_16x16x32_bf16(k00, qf[ks], c0a, 0, 0, 0);
            short8 k10 = *(const short8*)(kbase + rowb1 + cc0);
            c1a = __builtin_amdgcn_mfma_f32_16x16x32_bf16(k10, qf[ks], c1a, 0, 0, 0);
            const int cc1 = (((ks + 1) * 4 + hi) ^ sw) << 4;
            short8 k01 = *(const short8*)(kbase + rowb0 + cc1);
            c0b = __builtin_amdgcn_mfma_f32_16x16x32_bf16(k01, qf[ks + 1], c0b, 0, 0, 0);
            short8 k11 = *(const short8*)(kbase + rowb1 + cc1);
            c1b = __builtin_amdgcn_mfma_f32_16x16x32_bf16(k11, qf[ks + 1], c1b, 0, 0, 0);
        }
        __builtin_amdgcn_s_setprio(0);
        floatx4 c0 = c0a + c0b, c1 = c1a + c1b;

        // ---- static base-2 softmax: P = 2^(s' + b'), per-lane l partial --
        float p0[4], p1[4];
#pragma unroll
        for (int j = 0; j < 4; j++) {
            p0[j] = exp2_fast(c0[j] + biasLds[t * KVB + hi * 4 + j]);
            p1[j] = exp2_fast(c1[j] + biasLds[t * KVB + 16 + hi * 4 + j]);
            l_r += p0[j] + p1[j];
        }

        short8 pa;                                 // slots [p0, p1] match Vtp perm
#pragma unroll
        for (int j = 0; j < 4; j++) {
            pa[j]     = (short)f2bf(p0[j]);
            pa[4 + j] = (short)f2bf(p1[j]);
        }

        // ---- O += P @ V: B-frag = one b128 from permuted Vlds ----
        const char* vbase = (const char*)(Vlds0 + cur * (EMB * KVB));
        __builtin_amdgcn_s_setprio(1);
#pragma unroll
        for (int cf = 0; cf < 32; cf++) {
            const int col = cf * 16 + r16;
            short8 vf = *(const short8*)(vbase + col * 64 + ((hi ^ ((col >> 1) & 3)) << 4));
            oacc[cf] = __builtin_amdgcn_mfma_f32_16x16x32_bf16(pa, vf, oacc[cf], 0, 0, 0);
        }
        __builtin_amdgcn_s_setprio(0);

        __syncthreads();   // staged t+1 drained; buffers swappable
    }

    // ---- epilogue: unnormalized bf16 O partial + (m=12, l) per q-row ----
    bf16* pb = part + (long)bid * QTILE * EMB;
#pragma unroll
    for (int j = 0; j < 4; j++) {
        long row = wv * 16 + hi * 4 + j;
#pragma unroll
        for (int cf = 0; cf < 32; cf++)
            pb[row * EMB + cf * 16 + r16] = __float2bfloat16(oacc[cf][j]);
    }
    l_r += __shfl_xor(l_r, 16);        // deferred row-sum reduce (once)
    l_r += __shfl_xor(l_r, 32);
    if (hi == 0)
        ml[(long)bid * QTILE + wv * 16 + r16] = make_float2(12.0f, l_r);
}

// ---------------- combine the two KV halves (bf16 partials) ---------------
__global__ __launch_bounds__(128) void combine_halves(
    const bf16* __restrict__ part, const float2* __restrict__ ml,
    float* __restrict__ out)
{
    const int r  = blockIdx.x;              // 0..16383 global q-row
    const int b  = r >> 11;
    const int rb = r & 2047;
    const int qt = rb >> 7;
    const int rr = rb & 127;
    const int s0 = qt * 8 + b;              // slot of half 0
    const int s1 = s0 + 128;

    float2 ml0 = ml[(long)s0 * QTILE + rr];
    float2 ml1 = ml[(long)s1 * QTILE + rr];
    float M  = fmaxf(ml0.x, ml1.x);
    float w0 = __expf(ml0.x - M), w1 = __expf(ml1.x - M);
    float inv = 1.0f / (w0 * ml0.y + w1 * ml1.y);
    w0 *= inv; w1 *= inv;

    const ushort4_t* p0 = (const ushort4_t*)((const unsigned short*)part
                          + ((long)s0 * QTILE + rr) * EMB);
    const ushort4_t* p1 = (const ushort4_t*)((const unsigned short*)part
                          + ((long)s1 * QTILE + rr) * EMB);
    floatx4* po = (floatx4*)(out + (long)r * EMB);
    int c = threadIdx.x;                    // 128 threads x 4 = 512
    ushort4_t a = p0[c], d = p1[c];
    floatx4 o;
    o.x = bf2f(a.x) * w0 + bf2f(d.x) * w1;
    o.y = bf2f(a.y) * w0 + bf2f(d.y) * w1;
    o.z = bf2f(a.z) * w0 + bf2f(d.z) * w1;
    o.w = bf2f(a.w) * w0 + bf2f(d.w) * w1;
    po[c] = o;
}

// --------------------------------------------------------------------------
extern "C" void kernel_launch(void* const* d_in, const int* in_sizes, int n_in,
                              void* d_out, int out_size, void* d_ws, size_t ws_size,
                              hipStream_t stream)
{
    const float* feat = (const float*)d_in[0];
    const void*  mask = d_in[1];
    const float* Wq   = (const float*)d_in[2];
    const float* Wk   = (const float*)d_in[3];
    const float* Wv   = (const float*)d_in[4];
    float* out = (float*)d_out;

    const long M  = (long)BQ * SEQ;
    const long NE = M * EMB;
    const long NW = (long)EMB * EMB;

    char* ws = (char*)d_ws;
    size_t off = 0;
    auto carve = [&](size_t bytes) -> void* {
        void* p = ws + off;
        off = (off + bytes + 4095) & ~(size_t)4095;
        return p;
    };
    bf16*   Xb   = (bf16*)carve(NE * 2);
    bf16*   Wqb  = (bf16*)carve(NW * 2);
    bf16*   Wkb  = (bf16*)carve(NW * 2);
    bf16*   Wvb  = (bf16*)carve(NW * 2);
    bf16*   Qb   = (bf16*)carve(NE * 2);
    bf16*   Kb   = (bf16*)carve(NE * 2);
    bf16*   Vtp  = (bf16*)carve(NE * 2);
    float*  bias = (float*)carve(M * 4);
    bf16*   part = (bf16*)carve((long)256 * QTILE * EMB * 2);   // 32MB
    float2* ml   = (float2*)carve((long)256 * QTILE * 8);
    (void)ws_size; (void)in_sizes; (void)n_in; (void)out_size;

    // 512^-0.5 * log2(e) folded into Wq (base-2 softmax)
    const float qscale = 0.063758717254359f;

    prep<<<dim3(8976), dim3(256), 0, stream>>>(
        feat, Wq, Wk, Wv, mask, Xb, Wqb, Wkb, Wvb, bias, qscale);

    gemm_qkv<<<dim3(12, 128), dim3(256), 0, stream>>>(Xb, Wqb, Wkb, Wvb, Qb, Kb, Vtp);

    flash_attn<<<dim3(256), dim3(512), 0, stream>>>(Qb, Kb, Vtp, bias, part, ml);
    combine_halves<<<dim3(BQ * SEQ), dim3(128), 0, stream>>>(part, ml, out);
}